// Round 7
// baseline (162.386 us; speedup 1.0000x reference)
//
#include <hip/hip_runtime.h>

#define T_DIM 512
#define B_DIM 64
#define V_DIM 1296
#define S_DIM 30
#define LN2   0.6931471805599453f

typedef float v2f __attribute__((ext_vector_type(2)));

// DPP helper. bound_ctrl=true -> lanes with no source read 0.
template<int CTRL, bool BC>
__device__ __forceinline__ float dppf(float src, float old) {
    return __int_as_float(__builtin_amdgcn_update_dpp(
        __float_as_int(old), __float_as_int(src), CTRL, 0xF, 0xF, BC));
}

// ---------------------------------------------------------------------------
// Quad-packed scaled CTC forward, one 128-step quarter, read from GLOBAL
// compact (L2/L3-resident), 16-deep float4 register pipeline.
// Lane l (0..15): X=(alpha[4l],alpha[4l+2]) blanks, Y=(alpha[4l+1],alpha[4l+3])
// labels, scaled by 2^E. MODE 0: t==0 init. MODE 1: full. MODE 2: t<len pred.
// ---------------------------------------------------------------------------
template<int MODE>
__device__ __forceinline__ void scan_quarter(const float4* __restrict__ qp,
                                             int qbase, int len, int lane,
                                             v2f S, v2f& X, v2f& Y, int& E)
{
    const int jl = lane & 15;
    float4 buf[16];
#pragma unroll
    for (int i = 0; i < 16; ++i) buf[i] = qp[i * 16 + jl];

    float mred = 0.f;
    for (int j = 0; j < 8; ++j) {
#pragma unroll
        for (int ii = 0; ii < 16; ++ii) {
            float4 w = buf[ii];
            if (j < 7) buf[ii] = qp[((j + 1) * 16 + ii) * 16 + jl];  // refill +16

            if (MODE == 0 && j == 0 && ii == 0) {
                bool l0 = (lane == 0);
                X = (v2f){ l0 ? ldexpf(w.z, 64) : 0.f, 0.f };   // alpha[0]=w_blank
                Y = (v2f){ l0 ? ldexpf(w.x, 64) : 0.f, 0.f };   // alpha[1]=w_lab0
                E = 64;
            } else {
                float q3m = dppf<0x111, true>(Y.y, 0.f);        // alpha[4l-1]
                v2f Z  = { q3m, Y.x };
                v2f T1 = X + Z;
                v2f T2 = X + Y;
                v2f T3 = __builtin_elementwise_fma(S, Z, T2);
                v2f Wb = { w.z, w.w };
                v2f Wl = { w.x, w.y };
                v2f Xn = T1 * Wb;
                v2f Yn = T3 * Wl;
                if (MODE == 2) {
                    bool a = (qbase + j * 16 + ii) < len;
                    X = a ? Xn : X;
                    Y = a ? Yn : Y;
                } else { X = Xn; Y = Yn; }
            }
            // renorm window of 8: stale snapshot at 3, reduce 4..6, apply at 7
            if ((ii & 7) == 3) mred = fmaxf(fmaxf(X.x, X.y), fmaxf(Y.x, Y.y));
            if ((ii & 7) == 4) mred = fmaxf(mred, dppf<0x111, true>(mred, 0.f));
            if ((ii & 7) == 5) mred = fmaxf(mred, dppf<0x112, true>(mred, 0.f));
            if ((ii & 7) == 6) mred = fmaxf(mred, dppf<0x114, true>(mred, 0.f));
            if ((ii & 7) == 7) {
                mred = fmaxf(mred, dppf<0x118, true>(mred, 0.f)); // lane15=max(0..15)
                int e15 = (__builtin_amdgcn_readlane(__float_as_int(mred), 15) >> 23) & 0xFF;
                int sfx = 191 - e15;                              // recenter at 2^64
                X = (v2f){ ldexpf(X.x, sfx), ldexpf(X.y, sfx) };
                Y = (v2f){ ldexpf(Y.x, sfx), ldexpf(Y.y, sfx) };
                E += sfx;
            }
        }
    }
}

// ---------------------------------------------------------------------------
// One kernel, two roles:
//  blocks [0,256): gather block (b = bid>>2, quarter qt = bid&3) — 512 threads,
//    each handles 4 (t,slot) units: 12 independent scattered loads -> exp ->
//    coalesced float4 store to compact[b][t][slot]. Publishes the quarter via
//    device-scope release flag.
//  blocks [256,320): scanner (b = bid-256) — wave 0 acquire-polls quarter
//    flags and runs the serial recurrence from compact.
// ---------------------------------------------------------------------------
__global__ __launch_bounds__(512)
void ctc_split_kernel(const float* __restrict__ log_probs,
                      const int*   __restrict__ targets,
                      const int*   __restrict__ input_lengths,
                      const int*   __restrict__ target_lengths,
                      float4*      __restrict__ compact,   // (B,T,16)
                      float*       __restrict__ losses,    // (B)
                      unsigned*    __restrict__ flags,     // [256] + counter at [256]
                      float*       __restrict__ out)
{
    const int bid = blockIdx.x;
    if (bid < 256) {
        // ------------------------- gather role -------------------------
        const int b   = bid >> 2;
        const int qt  = bid & 3;
        const int tid = threadIdx.x;
        const int s   = tid & 15;          // lattice slot (lane) 0..15
        const int ri  = tid >> 4;          // row offset 0..31
        const int len = input_lengths[b];
        int lab0 = 0, lab1 = 0;
        if (s < 15) {
            lab0 = targets[b * S_DIM + 2 * s];
            lab1 = targets[b * S_DIM + 2 * s + 1];
        }
        const float* lpb = log_probs + (size_t)b * V_DIM;

        float va[4], vb[4], vc[4];
        int   trow[4];
        bool  act[4];
#pragma unroll
        for (int k = 0; k < 4; ++k) {      // issue all 12 loads for MLP
            int t = qt * 128 + k * 32 + ri;
            trow[k] = t;
            act[k]  = (t < len);
            if (act[k]) {
                const float* row = lpb + (size_t)t * (B_DIM * V_DIM);
                va[k] = row[lab0];
                vb[k] = row[lab1];
                vc[k] = row[0];
            }
        }
#pragma unroll
        for (int k = 0; k < 4; ++k) {
            if (act[k]) {
                float wb = __expf(vc[k]);
                float w0 = (s < 15) ? __expf(va[k]) : 0.f;  // lane15 labels absent
                float w1 = (s < 15) ? __expf(vb[k]) : 0.f;
                compact[((size_t)b * T_DIM + trow[k]) * 16 + s] =
                    make_float4(w0, w1, wb, wb);
            }
        }
        __threadfence();                   // publish stores at device scope
        __syncthreads();
        if (tid == 0)
            __hip_atomic_store(&flags[b * 4 + qt], 1u,
                               __ATOMIC_RELEASE, __HIP_MEMORY_SCOPE_AGENT);
    } else {
        // ------------------------- scanner role ------------------------
        const int tid = threadIdx.x;
        if (tid >= 64) return;             // one wave only; no barriers below
        const int b    = bid - 256;
        const int lane = tid;
        const int jl   = lane & 15;
        const int len  = input_lengths[b];
        const int tl   = target_lengths[b];

        float s0 = 0.f, s1 = 0.f;
        if (jl < 15) {
            int k0 = 2 * jl;
            int tc = targets[b * S_DIM + k0];
            int tp = (k0 > 0) ? targets[b * S_DIM + k0 - 1] : -1;  // -1 = blank
            s0 = (tc != tp) ? 1.f : 0.f;
            int tn = targets[b * S_DIM + k0 + 1];
            s1 = (tn != tc) ? 1.f : 0.f;
        }
        v2f S = { s0, s1 };
        v2f X = { 0.f, 0.f }, Y = { 0.f, 0.f };
        int E = 0;

        const float4* gb = compact + (size_t)b * T_DIM * 16;
        for (int q = 0; q < 4; ++q) {
            if (q * 128 >= len) break;     // wave-uniform
            unsigned it = 0;
            while (__hip_atomic_load(&flags[b * 4 + q], __ATOMIC_ACQUIRE,
                                     __HIP_MEMORY_SCOPE_AGENT) == 0u) {
                __builtin_amdgcn_s_sleep(2);
                if (++it > (1u << 24)) break;          // bounded spin (safety)
            }
            const float4* qp = gb + (size_t)q * 128 * 16;
            if (q == 0)                    scan_quarter<0>(qp, 0,       len, lane, S, X, Y, E);
            else if ((q + 1) * 128 <= len) scan_quarter<1>(qp, q * 128, len, lane, S, X, Y, E);
            else                           scan_quarter<2>(qp, q * 128, len, lane, S, X, Y, E);
        }

        // alpha[2*tl] (pos 60: lane15 X.x) and alpha[2*tl-1] (pos 59: lane14 Y.y)
        int pB_p = 2 * tl, pL_p = 2 * tl - 1;
        float vB = (pB_p & 2) ? ((pB_p & 1) ? Y.y : X.y) : ((pB_p & 1) ? Y.x : X.x);
        float vL = (pL_p & 2) ? ((pL_p & 1) ? Y.y : X.y) : ((pL_p & 1) ? Y.x : X.x);
        float pB = __shfl(vB, pB_p >> 2);
        float pL = __shfl(vL, pL_p >> 2);
        float loss = -LN2 * (__builtin_amdgcn_logf(pB + pL) - (float)E);
        if (!(loss < 1e29f)) loss = 0.f;   // zero_infinity (inf/NaN)
        loss /= (float)tl;

        unsigned* counter = flags + 256;
        unsigned old = 0;
        if (lane == 0) {
            losses[b] = loss;
            __threadfence();               // release per-block loss
            old = atomicAdd(counter, 1u);  // device scope
        }
        old = __shfl(old, 0);
        if (old == 63u) {                  // last scanner reduces, lane-parallel
            __threadfence();               // acquire
            float v = ((volatile const float*)losses)[lane];
#pragma unroll
            for (int off = 32; off >= 1; off >>= 1)
                v += __shfl_xor(v, off);
            if (lane == 0) out[0] = v * (1.f / (float)B_DIM);
        }
    }
}

extern "C" void kernel_launch(void* const* d_in, const int* in_sizes, int n_in,
                              void* d_out, int out_size, void* d_ws, size_t ws_size,
                              hipStream_t stream)
{
    const float* log_probs      = (const float*)d_in[0];
    const int*   targets        = (const int*)  d_in[1];
    const int*   input_lengths  = (const int*)  d_in[2];
    const int*   target_lengths = (const int*)  d_in[3];
    float*       out            = (float*)d_out;

    // ws layout: compact 8 MB | losses 256 B | flags[256]+counter (1 KB pad)
    float4*   compact = (float4*)d_ws;
    float*    losses  = (float*)((char*)d_ws + (size_t)8 * 1024 * 1024);
    unsigned* flags   = (unsigned*)((char*)d_ws + (size_t)8 * 1024 * 1024 + 1024);

    hipMemsetAsync(flags, 0, 257 * sizeof(unsigned), stream);  // capturable
    hipLaunchKernelGGL(ctc_split_kernel, dim3(320), dim3(512), 0, stream,
                       log_probs, targets, input_lengths, target_lengths,
                       compact, losses, flags, out);
}

// Round 8
// 36.094 us; speedup vs baseline: 4.4990x; 4.4990x over previous
//
#include <hip/hip_runtime.h>

#define T_DIM 512
#define B_DIM 64
#define V_DIM 1296
#define S_DIM 30
#define LN2   0.6931471805599453f

typedef float v2f __attribute__((ext_vector_type(2)));

// DPP helper. bound_ctrl=true -> lanes with no source read 0.
template<int CTRL, bool BC>
__device__ __forceinline__ float dppf(float src, float old) {
    return __int_as_float(__builtin_amdgcn_update_dpp(
        __float_as_int(old), __float_as_int(src), CTRL, 0xF, 0xF, BC));
}

// ---------------------------------------------------------------------------
// Quad-packed scaled CTC forward chunk (32 time steps) — proven in round 6.
// Lane l (0..15): X = (alpha[4l], alpha[4l+2])  [blank positions]
//                 Y = (alpha[4l+1], alpha[4l+3]) [label positions 2l, 2l+1]
// all scaled by 2^E. LDS row layout per lane: float4 (wl0, wl1, wb, wb).
// MODE 0: chunk 0 (t==0 init). MODE 1: full. MODE 2: per-step t<len predicate.
// ---------------------------------------------------------------------------
template<int MODE>
__device__ __forceinline__ void consume_chunk(const float4* __restrict__ ringc,
                                              int c, int len, int lane, v2f S,
                                              v2f& X, v2f& Y, int& E)
{
    const int jl = lane & 15;
    float4 buf[8];
#pragma unroll
    for (int i = 0; i < 8; ++i) buf[i] = ringc[i * 16 + jl];

    float mred = 0.f;
#pragma unroll
    for (int i = 0; i < 32; ++i) {
        float4 w = buf[i & 7];
        if (i + 8 < 32) buf[i & 7] = ringc[(i + 8) * 16 + jl];

        if (MODE == 0 && i == 0) {
            bool l0 = (lane == 0);
            X = (v2f){ l0 ? ldexpf(w.z, 64) : 0.f, 0.f };   // alpha[0] = w_blank
            Y = (v2f){ l0 ? ldexpf(w.x, 64) : 0.f, 0.f };   // alpha[1] = w_lab0
            E = 64;
        } else {
            float q3m = dppf<0x111, true>(Y.y, 0.f);        // alpha[4l-1] from lane l-1
            v2f Z  = { q3m, Y.x };                          // (alpha[4l-1], alpha[4l+1])
            v2f T1 = X + Z;                                 // (q0+q3m, q2+q1)
            v2f T2 = X + Y;                                 // (q0+q1,  q2+q3)
            v2f T3 = __builtin_elementwise_fma(S, Z, T2);   // + skip terms
            v2f Wb = { w.z, w.w };
            v2f Wl = { w.x, w.y };
            v2f Xn = T1 * Wb;
            v2f Yn = T3 * Wl;
            if (MODE == 2) {
                bool act = (c * 32 + i) < len;
                X = act ? Xn : X;
                Y = act ? Yn : Y;
            } else { X = Xn; Y = Yn; }
        }

        // renorm window of 8: snapshot at step 3 (stale), reduce spread over
        // steps 4..6 (off the recurrence chain), apply at step 7 (exact 2^s).
        if ((i & 7) == 3) mred = fmaxf(fmaxf(X.x, X.y), fmaxf(Y.x, Y.y));
        if ((i & 7) == 4) mred = fmaxf(mred, dppf<0x111, true>(mred, 0.f));
        if ((i & 7) == 5) mred = fmaxf(mred, dppf<0x112, true>(mred, 0.f));
        if ((i & 7) == 6) mred = fmaxf(mred, dppf<0x114, true>(mred, 0.f));
        if ((i & 7) == 7) {
            mred = fmaxf(mred, dppf<0x118, true>(mred, 0.f));  // lane15 = max(0..15)
            int e15 = (__builtin_amdgcn_readlane(__float_as_int(mred), 15) >> 23) & 0xFF;
            int s = 191 - e15;                               // recenter max at 2^64
            X = (v2f){ ldexpf(X.x, s), ldexpf(X.y, s) };
            Y = (v2f){ ldexpf(Y.x, s), ldexpf(Y.y, s) };
            E += s;
        }
    }
}

// ---------------------------------------------------------------------------
// Kernel 1: gather. 256 blocks (b = bid>>2, quarter = bid&3), 512 threads.
// Each thread: up to 12 independent scattered loads -> exp -> 4 coalesced
// float4 stores into compact[b][t][slot]. Also zeroes the K2 reduce counter.
// Kernel boundary (same stream) provides sync + coherence for K2.
// ---------------------------------------------------------------------------
__global__ __launch_bounds__(512)
void ctc_gather_kernel(const float* __restrict__ log_probs,
                       const int*   __restrict__ targets,
                       const int*   __restrict__ input_lengths,
                       float4*      __restrict__ compact,   // (B,T,16)
                       unsigned*    __restrict__ counter)
{
    const int bid = blockIdx.x;
    const int b   = bid >> 2;
    const int qt  = bid & 3;
    const int tid = threadIdx.x;
    const int s   = tid & 15;          // lattice slot 0..15
    const int ri  = tid >> 4;          // row offset 0..31
    const int len = input_lengths[b];
    if (bid == 0 && tid == 0) *counter = 0u;

    int lab0 = 0, lab1 = 0;
    if (s < 15) {
        lab0 = targets[b * S_DIM + 2 * s];
        lab1 = targets[b * S_DIM + 2 * s + 1];
    }
    const float* lpb = log_probs + (size_t)b * V_DIM;

    float va[4], vb[4], vc[4];
    int   trow[4];
    bool  act[4];
#pragma unroll
    for (int k = 0; k < 4; ++k) {      // issue all loads first (MLP)
        int t = qt * 128 + k * 32 + ri;
        trow[k] = t;
        act[k]  = (t < len);
        if (act[k]) {
            const float* row = lpb + (size_t)t * (B_DIM * V_DIM);
            va[k] = row[lab0];
            vb[k] = row[lab1];
            vc[k] = row[0];
        }
    }
#pragma unroll
    for (int k = 0; k < 4; ++k) {
        if (act[k]) {
            float wb = __expf(vc[k]);
            float w0 = (s < 15) ? __expf(va[k]) : 0.f;   // lane15 labels absent
            float w1 = (s < 15) ? __expf(vb[k]) : 0.f;
            compact[((size_t)b * T_DIM + trow[k]) * 16 + s] =
                make_float4(w0, w1, wb, wb);
        }
    }
}

// ---------------------------------------------------------------------------
// Kernel 2: scan. 64 blocks x 576 threads (round-6 proven structure).
// Waves 0-7 stream compact (coalesced, 1 float4/thread/chunk) into a 4-chunk
// LDS ring with a 2-chunk register lead; wave 8 runs the DPP recurrence.
// Raw s_barrier + lgkmcnt-only drains keep global loads in flight.
// ---------------------------------------------------------------------------
__global__ __launch_bounds__(576)
void ctc_scan_kernel(const float4* __restrict__ compact,
                     const int*    __restrict__ targets,
                     const int*    __restrict__ input_lengths,
                     const int*    __restrict__ target_lengths,
                     float*        __restrict__ losses,
                     unsigned*     __restrict__ counter,
                     float*        __restrict__ out)
{
    __shared__ float4 ring[4 * 512];                 // 4-chunk ring, 32 KB
    const int  b    = blockIdx.x;
    const int  tid  = threadIdx.x;
    const int  len  = input_lengths[b];
    const bool prod = (tid < 512);

    const float4* cb = compact + (size_t)b * T_DIM * 16;   // chunk k = cb[k*512 + tid]

    float4 fA = {0,0,0,0}, fB = {0,0,0,0};           // producer register lead
    const int lane = tid - 512;                      // scanner lane
    v2f X = {0.f, 0.f}, Y = {0.f, 0.f}, S = {0.f, 0.f};
    int E = 0;

    if (prod) {
        float4 t0 = cb[0 * 512 + tid];
        float4 t1 = cb[1 * 512 + tid];
        float4 t2 = cb[2 * 512 + tid];
        fA = cb[3 * 512 + tid];                      // 2 chunks of lead
        fB = cb[4 * 512 + tid];
        ring[0 * 512 + tid] = t0;
        ring[1 * 512 + tid] = t1;
        ring[2 * 512 + tid] = t2;
        asm volatile("s_waitcnt lgkmcnt(0)" ::: "memory");   // LDS-only drain
    } else {
        int lq = lane & 15;
        float s0 = 0.f, s1 = 0.f;
        if (lq < 15) {
            int k0 = 2 * lq;
            int tc = targets[b * S_DIM + k0];
            int tp = (k0 > 0) ? targets[b * S_DIM + k0 - 1] : -1;  // -1 = blank
            s0 = (tc != tp) ? 1.f : 0.f;
            int tn = targets[b * S_DIM + k0 + 1];
            s1 = (tn != tc) ? 1.f : 0.f;
        }
        S = (v2f){ s0, s1 };
    }
    __builtin_amdgcn_s_barrier();                    // raw barrier: no vmcnt drain
    __builtin_amdgcn_sched_barrier(0);

    for (int c = 0; c < 16; ++c) {
        if (prod) {
            if (c < 13) ring[((c + 3) & 3) * 512 + tid] = fA;   // loaded 2 iters ago
            float4 nl = {0,0,0,0};
            if (c < 11) nl = cb[(size_t)(c + 5) * 512 + tid];
            fA = fB; fB = nl;
            asm volatile("s_waitcnt lgkmcnt(0)" ::: "memory");  // LDS-only drain
        } else {
            const float4* ringc = &ring[(c & 3) * 512];
            if (c == 0)                   consume_chunk<0>(ringc, c, len, lane, S, X, Y, E);
            else if ((c + 1) * 32 <= len) consume_chunk<1>(ringc, c, len, lane, S, X, Y, E);
            else if (c * 32 < len)        consume_chunk<2>(ringc, c, len, lane, S, X, Y, E);
        }
        __builtin_amdgcn_s_barrier();
        __builtin_amdgcn_sched_barrier(0);
    }

    if (!prod) {
        // alpha[2*tl] (pos 60: lane15 X.x) and alpha[2*tl-1] (pos 59: lane14 Y.y)
        int tl   = target_lengths[b];
        int pB_p = 2 * tl, pL_p = 2 * tl - 1;
        float vB = (pB_p & 2) ? ((pB_p & 1) ? Y.y : X.y) : ((pB_p & 1) ? Y.x : X.x);
        float vL = (pL_p & 2) ? ((pL_p & 1) ? Y.y : X.y) : ((pL_p & 1) ? Y.x : X.x);
        float pB = __shfl(vB, pB_p >> 2);
        float pL = __shfl(vL, pL_p >> 2);
        float loss = -LN2 * (__builtin_amdgcn_logf(pB + pL) - (float)E);
        if (!(loss < 1e29f)) loss = 0.f;             // zero_infinity (inf/NaN)
        loss /= (float)tl;

        unsigned old = 0;
        if (lane == 0) {
            losses[b] = loss;
            __threadfence();                         // release per-block loss
            old = atomicAdd(counter, 1u);            // device scope
        }
        old = __shfl(old, 0);
        if (old == 63u) {                            // last block reduces, lane-parallel
            __threadfence();                         // acquire
            float v = ((volatile const float*)losses)[lane];
#pragma unroll
            for (int off = 32; off >= 1; off >>= 1)
                v += __shfl_xor(v, off);
            if (lane == 0) out[0] = v * (1.f / (float)B_DIM);
        }
    }
}

extern "C" void kernel_launch(void* const* d_in, const int* in_sizes, int n_in,
                              void* d_out, int out_size, void* d_ws, size_t ws_size,
                              hipStream_t stream)
{
    const float* log_probs      = (const float*)d_in[0];
    const int*   targets        = (const int*)  d_in[1];
    const int*   input_lengths  = (const int*)  d_in[2];
    const int*   target_lengths = (const int*)  d_in[3];
    float*       out            = (float*)d_out;

    // ws layout: compact 8 MB | losses (256 B) | counter
    float4*   compact = (float4*)d_ws;
    float*    losses  = (float*)((char*)d_ws + (size_t)8 * 1024 * 1024);
    unsigned* counter = (unsigned*)((char*)d_ws + (size_t)8 * 1024 * 1024 + 256);

    hipLaunchKernelGGL(ctc_gather_kernel, dim3(256), dim3(512), 0, stream,
                       log_probs, targets, input_lengths, compact, counter);
    hipLaunchKernelGGL(ctc_scan_kernel, dim3(B_DIM), dim3(576), 0, stream,
                       compact, targets, input_lengths, target_lengths,
                       losses, counter, out);
}